// Round 3
// baseline (349.484 us; speedup 1.0000x reference)
//
#include <hip/hip_runtime.h>
#include <hip/hip_bf16.h>

// Problem: B=16, N=4096, D=768, M=8
//   xn = LayerNorm(x) * gamma + beta          [B,N,D]
//   sim = (queries @ xn^T) * D^-0.5           [B,M,N]
//   attn = softmax(sim, axis=-1)
//   out = attn @ xn                           [B,M,D]
// All I/O fp32 (round-1: bf16 input decode -> NaN => inputs fp32;
// round-2: bf16 output write -> absmax 0.29 > max|ref| => output read as fp32).

#define B_ 16
#define N_ 4096
#define D_ 768
#define M_ 8
#define EPS_ 1e-3f
#define SCALE_ 0.03608439182435161f  // 768^-0.5

// ws layout (floats)
#define SIM_OFF   0            // B*M*N = 524288 floats
#define MEAN_OFF  524288       // B*N   =  65536
#define RSTD_OFF  589824       // B*N   =  65536
// total 655360 floats = 2.5 MiB

// ---------------- kernel 1: LayerNorm stats + sim = q . xn ----------------
// one wave (64 lanes) per row; each lane owns 12 columns (3 x float4 loads).
__global__ __launch_bounds__(256) void k_ln_sim(
    const float* __restrict__ x,
    const float* __restrict__ q,
    const float* __restrict__ gm,
    const float* __restrict__ bt,
    float* __restrict__ sim, float* __restrict__ meanb, float* __restrict__ rstdb)
{
    const int lane = threadIdx.x & 63;
    const int gw   = blockIdx.x * 4 + (threadIdx.x >> 6);
    const int total_waves = gridDim.x * 4;

    // per-lane fixed columns: c = (lane + i*64)*4 + j
    float g[12], bb[12], qr[8][12];
#pragma unroll
    for (int i = 0; i < 3; i++) {
        const int c4 = (lane + i * 64) * 4;
        float4 gv = *(const float4*)(gm + c4);
        float4 bv = *(const float4*)(bt + c4);
        g[i * 4 + 0] = gv.x; g[i * 4 + 1] = gv.y; g[i * 4 + 2] = gv.z; g[i * 4 + 3] = gv.w;
        bb[i * 4 + 0] = bv.x; bb[i * 4 + 1] = bv.y; bb[i * 4 + 2] = bv.z; bb[i * 4 + 3] = bv.w;
#pragma unroll
        for (int m = 0; m < 8; m++) {
            float4 qv = *(const float4*)(q + m * D_ + c4);
            qr[m][i * 4 + 0] = qv.x; qr[m][i * 4 + 1] = qv.y;
            qr[m][i * 4 + 2] = qv.z; qr[m][i * 4 + 3] = qv.w;
        }
    }

    for (int row = gw; row < B_ * N_; row += total_waves) {
        const float* xr = x + (size_t)row * D_;
        float v[12];
#pragma unroll
        for (int i = 0; i < 3; i++) {
            float4 p = *(const float4*)(xr + (lane + i * 64) * 4);
            v[i * 4 + 0] = p.x; v[i * 4 + 1] = p.y;
            v[i * 4 + 2] = p.z; v[i * 4 + 3] = p.w;
        }
        float s = 0.f, s2 = 0.f;
#pragma unroll
        for (int k = 0; k < 12; k++) { s += v[k]; s2 += v[k] * v[k]; }
#pragma unroll
        for (int mask = 32; mask; mask >>= 1) {
            s  += __shfl_xor(s,  mask, 64);
            s2 += __shfl_xor(s2, mask, 64);
        }
        const float mean = s * (1.0f / 768.0f);
        float var = s2 * (1.0f / 768.0f) - mean * mean;
        var = fmaxf(var, 0.0f);
        const float rstd = rsqrtf(var + EPS_);

        float acc[8];
#pragma unroll
        for (int m = 0; m < 8; m++) acc[m] = 0.f;
#pragma unroll
        for (int k = 0; k < 12; k++) {
            const float xn = (v[k] - mean) * rstd * g[k] + bb[k];
#pragma unroll
            for (int m = 0; m < 8; m++) acc[m] = fmaf(qr[m][k], xn, acc[m]);
        }
#pragma unroll
        for (int mask = 32; mask; mask >>= 1)
#pragma unroll
            for (int m = 0; m < 8; m++) acc[m] += __shfl_xor(acc[m], mask, 64);

        if (lane == 0) {
            const int b = row >> 12, n = row & (N_ - 1);
            meanb[row] = mean;
            rstdb[row] = rstd;
#pragma unroll
            for (int m = 0; m < 8; m++)
                sim[(size_t)((b * 8 + m) << 12) + n] = acc[m] * SCALE_;
        }
    }
}

// ---------------- kernel 2: softmax over N per (b,m) ----------------
__global__ __launch_bounds__(256) void k_softmax(float* __restrict__ sim)
{
    float* p = sim + (size_t)blockIdx.x * N_;   // blockIdx 0..127 = (b*8+m)
    const int t = threadIdx.x;
    const int lane = t & 63, wave = t >> 6;
    __shared__ float red[4];

    float v[16];
    float mx = -3.4e38f;
#pragma unroll
    for (int i = 0; i < 16; i++) { v[i] = p[t + i * 256]; mx = fmaxf(mx, v[i]); }
#pragma unroll
    for (int mask = 32; mask; mask >>= 1) mx = fmaxf(mx, __shfl_xor(mx, mask, 64));
    if (lane == 0) red[wave] = mx;
    __syncthreads();
    mx = fmaxf(fmaxf(red[0], red[1]), fmaxf(red[2], red[3]));
    __syncthreads();

    float s = 0.f;
#pragma unroll
    for (int i = 0; i < 16; i++) { v[i] = __expf(v[i] - mx); s += v[i]; }
#pragma unroll
    for (int mask = 32; mask; mask >>= 1) s += __shfl_xor(s, mask, 64);
    if (lane == 0) red[wave] = s;
    __syncthreads();
    s = red[0] + red[1] + red[2] + red[3];

    const float inv = 1.0f / s;
#pragma unroll
    for (int i = 0; i < 16; i++) p[t + i * 256] = v[i] * inv;
}

// ---------------- kernel 3: out += attn @ xn (recompute xn) ----------------
// grid: 16 b * 16 chunks of 256 rows; 256 threads; thread owns cols t, t+256, t+512.
// Accumulates directly into d_out (fp32) via atomicAdd; d_out zeroed in launch.
__global__ __launch_bounds__(256) void k_out(
    const float* __restrict__ x,
    const float* __restrict__ gm,
    const float* __restrict__ bt,
    const float* __restrict__ sim,
    const float* __restrict__ meanb,
    const float* __restrict__ rstdb,
    float* __restrict__ out)
{
    __shared__ float attn_s[8 * 256];
    __shared__ float mean_s[256];
    __shared__ float rstd_s[256];

    const int b = blockIdx.x >> 4;
    const int n0 = (blockIdx.x & 15) * 256;
    const int t = threadIdx.x;

#pragma unroll
    for (int k = 0; k < 8; k++) {
        const int idx = t + k * 256;              // idx = m*256 + nn
        attn_s[idx] = sim[(size_t)((b * 8 + (idx >> 8)) << 12) + n0 + (idx & 255)];
    }
    mean_s[t] = meanb[b * N_ + n0 + t];
    rstd_s[t] = rstdb[b * N_ + n0 + t];
    __syncthreads();

    const float g0 = gm[t],       bb0 = bt[t];
    const float g1 = gm[t + 256], bb1 = bt[t + 256];
    const float g2 = gm[t + 512], bb2 = bt[t + 512];

    float acc[8][3];
#pragma unroll
    for (int m = 0; m < 8; m++)
#pragma unroll
        for (int j = 0; j < 3; j++) acc[m][j] = 0.f;

    const float* xb = x + ((size_t)(b * N_ + n0)) * D_;
    for (int nn = 0; nn < 256; nn++) {
        const float* xr = xb + (size_t)nn * D_;
        const float mu = mean_s[nn], rs = rstd_s[nn];
        const float xn0 = (xr[t]       - mu) * rs * g0 + bb0;
        const float xn1 = (xr[t + 256] - mu) * rs * g1 + bb1;
        const float xn2 = (xr[t + 512] - mu) * rs * g2 + bb2;
#pragma unroll
        for (int m = 0; m < 8; m++) {
            const float a = attn_s[m * 256 + nn];
            acc[m][0] = fmaf(a, xn0, acc[m][0]);
            acc[m][1] = fmaf(a, xn1, acc[m][1]);
            acc[m][2] = fmaf(a, xn2, acc[m][2]);
        }
    }

#pragma unroll
    for (int m = 0; m < 8; m++) {
        float* o = out + (size_t)(b * 8 + m) * D_;
        atomicAdd(o + t,       acc[m][0]);
        atomicAdd(o + t + 256, acc[m][1]);
        atomicAdd(o + t + 512, acc[m][2]);
    }
}

extern "C" void kernel_launch(void* const* d_in, const int* in_sizes, int n_in,
                              void* d_out, int out_size, void* d_ws, size_t ws_size,
                              hipStream_t stream)
{
    const float* x  = (const float*)d_in[0];
    const float* q  = (const float*)d_in[1];
    const float* gm = (const float*)d_in[2];
    const float* bt = (const float*)d_in[3];
    float* out = (float*)d_out;

    float* ws    = (float*)d_ws;
    float* sim   = ws + SIM_OFF;
    float* meanb = ws + MEAN_OFF;
    float* rstdb = ws + RSTD_OFF;

    hipMemsetAsync(out, 0, (size_t)B_ * M_ * D_ * sizeof(float), stream);

    k_ln_sim<<<2048, 256, 0, stream>>>(x, q, gm, bt, sim, meanb, rstdb);
    k_softmax<<<B_ * M_, 256, 0, stream>>>(sim);
    k_out<<<B_ * 16, 256, 0, stream>>>(x, gm, bt, sim, meanb, rstdb, out);
}

// Round 4
// 333.144 us; speedup vs baseline: 1.0490x; 1.0490x over previous
//
#include <hip/hip_runtime.h>
#include <hip/hip_bf16.h>

// Problem: B=16, N=4096, D=768, M=8
//   xn = LayerNorm(x) * gamma + beta          [B,N,D]
//   sim = (queries @ xn^T) * D^-0.5           [B,M,N]
//   attn = softmax(sim, axis=-1)
//   out = attn @ xn                           [B,M,D]
// All I/O fp32. Compute fp32.

#define B_ 16
#define N_ 4096
#define D_ 768
#define M_ 8
#define EPS_ 1e-3f
#define SCALE_ 0.03608439182435161f  // 768^-0.5

// ws layout (floats)
#define SIM_OFF   0            // B*M*N = 524288 floats
#define MEAN_OFF  524288       // B*N   =  65536
#define RSTD_OFF  589824       // B*N   =  65536
#define SMAX_OFF  655360       // B*M   =    128
#define SINV_OFF  655488       // B*M   =    128

// ---------------- kernel 1: LayerNorm stats + sim = q . xn ----------------
// one wave (64 lanes) per row; each lane owns 12 columns (3 x float4 loads).
__global__ __launch_bounds__(256) void k_ln_sim(
    const float* __restrict__ x,
    const float* __restrict__ q,
    const float* __restrict__ gm,
    const float* __restrict__ bt,
    float* __restrict__ sim, float* __restrict__ meanb, float* __restrict__ rstdb)
{
    const int lane = threadIdx.x & 63;
    const int gw   = blockIdx.x * 4 + (threadIdx.x >> 6);
    const int total_waves = gridDim.x * 4;

    float g[12], bb[12], qr[8][12];
#pragma unroll
    for (int i = 0; i < 3; i++) {
        const int c4 = (lane + i * 64) * 4;
        float4 gv = *(const float4*)(gm + c4);
        float4 bv = *(const float4*)(bt + c4);
        g[i * 4 + 0] = gv.x; g[i * 4 + 1] = gv.y; g[i * 4 + 2] = gv.z; g[i * 4 + 3] = gv.w;
        bb[i * 4 + 0] = bv.x; bb[i * 4 + 1] = bv.y; bb[i * 4 + 2] = bv.z; bb[i * 4 + 3] = bv.w;
#pragma unroll
        for (int m = 0; m < 8; m++) {
            float4 qv = *(const float4*)(q + m * D_ + c4);
            qr[m][i * 4 + 0] = qv.x; qr[m][i * 4 + 1] = qv.y;
            qr[m][i * 4 + 2] = qv.z; qr[m][i * 4 + 3] = qv.w;
        }
    }

    for (int row = gw; row < B_ * N_; row += total_waves) {
        const float* xr = x + (size_t)row * D_;
        float v[12];
#pragma unroll
        for (int i = 0; i < 3; i++) {
            float4 p = *(const float4*)(xr + (lane + i * 64) * 4);
            v[i * 4 + 0] = p.x; v[i * 4 + 1] = p.y;
            v[i * 4 + 2] = p.z; v[i * 4 + 3] = p.w;
        }
        float s = 0.f, s2 = 0.f;
#pragma unroll
        for (int k = 0; k < 12; k++) { s += v[k]; s2 += v[k] * v[k]; }
#pragma unroll
        for (int mask = 32; mask; mask >>= 1) {
            s  += __shfl_xor(s,  mask, 64);
            s2 += __shfl_xor(s2, mask, 64);
        }
        const float mean = s * (1.0f / 768.0f);
        float var = s2 * (1.0f / 768.0f) - mean * mean;
        var = fmaxf(var, 0.0f);
        const float rstd = rsqrtf(var + EPS_);

        float acc[8];
#pragma unroll
        for (int m = 0; m < 8; m++) acc[m] = 0.f;
#pragma unroll
        for (int k = 0; k < 12; k++) {
            const float xn = (v[k] - mean) * rstd * g[k] + bb[k];
#pragma unroll
            for (int m = 0; m < 8; m++) acc[m] = fmaf(qr[m][k], xn, acc[m]);
        }
#pragma unroll
        for (int mask = 32; mask; mask >>= 1)
#pragma unroll
            for (int m = 0; m < 8; m++) acc[m] += __shfl_xor(acc[m], mask, 64);

        if (lane == 0) {
            const int b = row >> 12, n = row & (N_ - 1);
            meanb[row] = mean;
            rstdb[row] = rstd;
#pragma unroll
            for (int m = 0; m < 8; m++)
                sim[(size_t)((b * 8 + m) << 12) + n] = acc[m] * SCALE_;
        }
    }
}

// ---------------- kernel 2: per-(b,m) softmax max and 1/sum ----------------
__global__ __launch_bounds__(256) void k_stats(
    const float* __restrict__ sim, float* __restrict__ smax, float* __restrict__ sinv)
{
    const float* p = sim + (size_t)blockIdx.x * N_;   // blockIdx 0..127 = b*8+m
    const int t = threadIdx.x;
    const int lane = t & 63, wave = t >> 6;
    __shared__ float red[4];

    float v[16];
    float mx = -3.4e38f;
#pragma unroll
    for (int i = 0; i < 16; i++) { v[i] = p[t + i * 256]; mx = fmaxf(mx, v[i]); }
#pragma unroll
    for (int mask = 32; mask; mask >>= 1) mx = fmaxf(mx, __shfl_xor(mx, mask, 64));
    if (lane == 0) red[wave] = mx;
    __syncthreads();
    mx = fmaxf(fmaxf(red[0], red[1]), fmaxf(red[2], red[3]));
    __syncthreads();

    float s = 0.f;
#pragma unroll
    for (int i = 0; i < 16; i++) s += __expf(v[i] - mx);
#pragma unroll
    for (int mask = 32; mask; mask >>= 1) s += __shfl_xor(s, mask, 64);
    if (lane == 0) red[wave] = s;
    __syncthreads();
    if (t == 0) {
        s = red[0] + red[1] + red[2] + red[3];
        smax[blockIdx.x] = mx;
        sinv[blockIdx.x] = 1.0f / s;
    }
}

// ---------------- kernel 3: out += attn @ xn (recompute xn) ----------------
// grid: 16 b * 64 chunks of 64 rows = 1024 blocks (4/CU, 16 waves/CU).
// thread owns cols t, t+256, t+512; weights exp-normalized inline.
__global__ __launch_bounds__(256) void k_out(
    const float* __restrict__ x,
    const float* __restrict__ gm,
    const float* __restrict__ bt,
    const float* __restrict__ sim,
    const float* __restrict__ meanb,
    const float* __restrict__ rstdb,
    const float* __restrict__ smax,
    const float* __restrict__ sinv,
    float* __restrict__ out)
{
    __shared__ float w_s[8 * 64];
    __shared__ float mean_s[64];
    __shared__ float rstd_s[64];

    const int b = blockIdx.x >> 6;
    const int n0 = (blockIdx.x & 63) * 64;
    const int t = threadIdx.x;

#pragma unroll
    for (int k = 0; k < 2; k++) {
        const int idx = t + k * 256;              // idx = m*64 + nn
        const int m = idx >> 6, nn = idx & 63;
        const float v = sim[(size_t)((b * 8 + m) << 12) + n0 + nn];
        w_s[idx] = __expf(v - smax[b * 8 + m]) * sinv[b * 8 + m];
    }
    if (t < 64) {
        mean_s[t] = meanb[b * N_ + n0 + t];
        rstd_s[t] = rstdb[b * N_ + n0 + t];
    }
    __syncthreads();

    const float g0 = gm[t],       bb0 = bt[t];
    const float g1 = gm[t + 256], bb1 = bt[t + 256];
    const float g2 = gm[t + 512], bb2 = bt[t + 512];

    float acc[8][3];
#pragma unroll
    for (int m = 0; m < 8; m++)
#pragma unroll
        for (int j = 0; j < 3; j++) acc[m][j] = 0.f;

    const float* xb = x + ((size_t)(b * N_ + n0)) * D_;
#pragma unroll 4
    for (int nn = 0; nn < 64; nn++) {
        const float* xr = xb + (size_t)nn * D_;
        const float mu = mean_s[nn], rs = rstd_s[nn];
        const float xn0 = (xr[t]       - mu) * rs * g0 + bb0;
        const float xn1 = (xr[t + 256] - mu) * rs * g1 + bb1;
        const float xn2 = (xr[t + 512] - mu) * rs * g2 + bb2;
#pragma unroll
        for (int m = 0; m < 8; m++) {
            const float a = w_s[m * 64 + nn];
            acc[m][0] = fmaf(a, xn0, acc[m][0]);
            acc[m][1] = fmaf(a, xn1, acc[m][1]);
            acc[m][2] = fmaf(a, xn2, acc[m][2]);
        }
    }

    // rotate m-order per block to spread atomic contention
#pragma unroll
    for (int mm = 0; mm < 8; mm++) {
        const int m = (mm + (blockIdx.x & 7)) & 7;
        float* o = out + (size_t)(b * 8 + m) * D_;
        atomicAdd(o + t,       acc[m][0]);
        atomicAdd(o + t + 256, acc[m][1]);
        atomicAdd(o + t + 512, acc[m][2]);
    }
}

extern "C" void kernel_launch(void* const* d_in, const int* in_sizes, int n_in,
                              void* d_out, int out_size, void* d_ws, size_t ws_size,
                              hipStream_t stream)
{
    const float* x  = (const float*)d_in[0];
    const float* q  = (const float*)d_in[1];
    const float* gm = (const float*)d_in[2];
    const float* bt = (const float*)d_in[3];
    float* out = (float*)d_out;

    float* ws    = (float*)d_ws;
    float* sim   = ws + SIM_OFF;
    float* meanb = ws + MEAN_OFF;
    float* rstdb = ws + RSTD_OFF;
    float* smax  = ws + SMAX_OFF;
    float* sinv  = ws + SINV_OFF;

    hipMemsetAsync(out, 0, (size_t)B_ * M_ * D_ * sizeof(float), stream);

    k_ln_sim<<<2048, 256, 0, stream>>>(x, q, gm, bt, sim, meanb, rstdb);
    k_stats<<<B_ * M_, 256, 0, stream>>>(sim, smax, sinv);
    k_out<<<B_ * 64, 256, 0, stream>>>(x, gm, bt, sim, meanb, rstdb, smax, sinv, out);
}